// Round 7
// baseline (5083.757 us; speedup 1.0000x reference)
//
#include <hip/hip_runtime.h>
#include <math.h>

#define DD 128
#define HH 256
#define NS 300
#define BB 512
#define NBLK 256   // rollout blocks (2 rows each)
#define TPB 1024
#define NPO (301*64)

// Dynamic-LDS float offsets for k_rollout (1024-thread version)
#define OFF_W1Q   0        // 8192 float4 = 32768 floats: [k4 in 32][hj in 256]
#define OFF_XS    32768    // [2][128]
#define OFF_HS    33024    // [2][256]  (also reused as nv buffer, general path)
#define OFF_WV    33536    // [2][128]
#define OFF_SCR   33792    // 4096-float phase-unioned partial scratch
#define OFF_RED   37888    // 16
#define SMEM_FLOATS 37904
#define SMEM_BYTES (SMEM_FLOATS*4)

__device__ __forceinline__ float tsf(int t){ return (float)((double)t*(1.0/(double)NS)); }

__device__ __forceinline__ float wave_red(float v){
#pragma unroll
  for(int o=32;o>0;o>>=1) v += __shfl_down(v,o);
  return v;
}
__device__ __forceinline__ float fma4(float4 a, float4 b, float acc){
  acc = fmaf(a.x,b.x,acc); acc = fmaf(a.y,b.y,acc);
  acc = fmaf(a.z,b.z,acc); acc = fmaf(a.w,b.w,acc); return acc;
}

// ---- pre1: identity flag + (general) Gauss-Jordan inverse -> SIT = sigma^-T
__global__ __launch_bounds__(256) void k_pre1(
    const float* __restrict__ sigma,
    float* __restrict__ SIT, float* __restrict__ AUG, int* __restrict__ FLG)
{
  const int j = threadIdx.x;
  __shared__ int s_ok; __shared__ int s_p; __shared__ float s_fac[DD];
  if (j == 0) s_ok = 1;
  __syncthreads();
  bool ok = true;
  for (int idx = j; idx < DD*DD; idx += 256) {
    const int r = idx >> 7, c = idx & 127;
    if (sigma[idx] != (r==c ? 1.f : 0.f)) ok = false;
  }
  if (!ok) s_ok = 0;
  __syncthreads();
  const bool ident = (s_ok != 0);
  if (j == 0) *FLG = ident ? 1 : 0;
  if (ident) {
    for (int idx = j; idx < DD*DD; idx += 256) {
      const int r = idx >> 7, c = idx & 127;
      SIT[idx] = (r==c) ? 1.f : 0.f;
    }
    return;
  }
  for (int idx = j; idx < DD*256; idx += 256) {
    const int r = idx >> 8, c = idx & 255;
    AUG[idx] = (c < DD) ? sigma[r*DD + c] : ((c-DD)==r ? 1.f : 0.f);
  }
  __syncthreads();
  for (int c = 0; c < DD; ++c) {
    if (j == 0) {
      int p = c; float best = fabsf(AUG[c*256 + c]);
      for (int r2 = c+1; r2 < DD; ++r2) {
        const float v = fabsf(AUG[r2*256 + c]);
        if (v > best) { best = v; p = r2; }
      }
      s_p = p;
    }
    __syncthreads();
    const int p = s_p;
    if (p != c) {
      const float tmp = AUG[c*256 + j];
      AUG[c*256 + j] = AUG[p*256 + j];
      AUG[p*256 + j] = tmp;
    }
    __syncthreads();
    const float pd = AUG[c*256 + c];
    const float rowv = AUG[c*256 + j];
    __syncthreads();
    AUG[c*256 + j] = rowv / pd;
    if (j < DD) s_fac[j] = (j == c) ? 0.f : AUG[j*256 + c];
    __syncthreads();
    const float prj = AUG[c*256 + j];
    for (int r2 = 0; r2 < DD; ++r2) {
      if (r2 != c) AUG[r2*256 + j] -= s_fac[r2] * prj;
    }
    __syncthreads();
  }
  for (int idx = j; idx < DD*DD; idx += 256) {
    const int j2 = idx >> 7, k = idx & 127;
    SIT[idx] = AUG[k*256 + DD + j2];
  }
}

// ---- pre2: M2 rows (-A @ sigma^-T) + sigma^T rows (k_obj needs SG2row)
__global__ __launch_bounds__(256) void k_pre2(
    const float* __restrict__ A, const float* __restrict__ sigma,
    const float* __restrict__ SIT, const int* __restrict__ FLG,
    float* __restrict__ M2row, float* __restrict__ SG2row)
{
  const int g = blockIdx.x*256 + threadIdx.x;
  const int gs = gridDim.x*256;
  const bool ident = (*FLG != 0);
  for (int idx = g; idx < DD*DD; idx += gs) {
    const int i2 = idx >> 7, k = idx & 127;
    SG2row[idx] = sigma[k*DD + i2];
    float m;
    if (ident) m = -A[idx];
    else {
      float acc = 0.f;
      for (int j = 0; j < DD; ++j) acc = fmaf(A[i2*DD + j], SIT[j*DD + k], acc);
      m = -acc;
    }
    M2row[idx] = m;
  }
}

// ---- rollout: 256 blocks x 1024 threads, 2 trajectories per block.
// W1 in LDS (128KB). Per-thread invariants sized for the 128-VGPR budget the
// allocator enforces at this block size: W2 32-wide slice (8xf4) + A-or-P
// quarter row (8xf4) = 64 floats. ident M2@wv = -(A@wv) reuses A regs.
__global__ __launch_bounds__(TPB)
void k_rollout(
    const float* __restrict__ x0, const float* __restrict__ sigma,
    const float* __restrict__ W1, const float* __restrict__ b1,
    const float* __restrict__ W2, const float* __restrict__ b2,
    const float* __restrict__ noises,
    const float* __restrict__ Am, const float* __restrict__ Pm,
    const float* __restrict__ Qm,
    const float* __restrict__ M2row, const int* __restrict__ FLG,
    float* __restrict__ U, float* __restrict__ TL,
    float* __restrict__ TGT, float* __restrict__ WGT)
{
  extern __shared__ float sm[];
  float4* W1q = (float4*)(sm + OFF_W1Q);
  float*  xs  = sm + OFF_XS;
  float*  hs  = sm + OFF_HS;
  float*  wv  = sm + OFF_WV;
  float*  scr = sm + OFF_SCR;
  float*  red = sm + OFF_RED;
  float4* xs4 = (float4*)xs;   // row r at f4-offset r*32
  float4* hs4 = (float4*)hs;   // row r at f4-offset r*64
  float4* wv4 = (float4*)wv;

  const int tid = threadIdx.x;
  const int hj = tid & 255, hg = tid >> 8;   // layer-1 mapping (hg in 0..3)
  const int i  = tid & 127, g  = tid >> 7;   // layer-2 / matvec mapping (g in 0..7)
  const int r2 = g;                          // row index when tid<256
  const int b0 = blockIdx.x * 2;
  const bool ident = (*FLG != 0);

  // --- prologue: W1 -> LDS (k-quads); W2/A/P slices -> registers
  for (int idx = tid; idx < 8192; idx += TPB) {
    const int k4 = idx >> 8, h = idx & 255;
    float4 w;
    w.x = W1[(4*k4 + 1)*HH + h];
    w.y = W1[(4*k4 + 2)*HH + h];
    w.z = W1[(4*k4 + 3)*HH + h];
    w.w = W1[(4*k4 + 4)*HH + h];
    W1q[idx] = w;
  }
  const float w1t = W1[hj];   // time-row weight (used by hg==0)
  const float b1c = b1[hj];
  const float b2i = b2[i];

  float4 w2r[8];
#pragma unroll
  for (int m = 0; m < 8; ++m) {
    const int k = g*32 + 4*m;
    w2r[m] = make_float4(W2[(k+0)*DD+i], W2[(k+1)*DD+i], W2[(k+2)*DD+i], W2[(k+3)*DD+i]);
  }
  float4 wr[8];   // g<4: A row quarter; g>=4: P row quarter
  {
    const float* src = (g < 4) ? Am : Pm;
#pragma unroll
    for (int m = 0; m < 8; ++m)
      wr[m] = *(const float4*)(src + i*DD + (g&3)*32 + 4*m);
  }
  if (tid < 256) xs[tid] = x0[i];

  float lwloc = 0.f, u_reg = 0.f, nz = 0.f;

  for (int t = 0; t <= NS; ++t) {
    __syncthreads();                                   // [A] xs (and W1q) ready
    const float t0 = tsf(t);
    const float dt = tsf(t+1) - t0;
    const float sdt = sqrtf(dt);
    if (tid < 256) {
      nz = (t < NS) ? noises[((size_t)t*BB + b0 + r2)*DD + i] : 0.f;
    }
    // --- layer 1: thread (hg,hj) quarter-dot, both rows; W1 from LDS
    {
      float a0 = (hg == 0) ? t0*w1t : 0.f;
      float a1 = a0;
#pragma unroll
      for (int m = 0; m < 8; ++m) {
        const float4 w = W1q[(hg*8 + m)*256 + hj];
        a0 = fma4(w, xs4[hg*8 + m], a0);        // broadcast reads (free)
        a1 = fma4(w, xs4[32 + hg*8 + m], a1);
      }
      scr[hg*512 + hj]       = a0;              // p2[hg][r][hj]
      scr[hg*512 + 256 + hj] = a1;
    }
    __syncthreads();                                   // [B]
    if (tid < 512) {
      const int rr = tid >> 8, cc = tid & 255;
      hs[rr*256 + cc] = tanhf(scr[rr*256+cc] + scr[512+rr*256+cc]
                            + scr[1024+rr*256+cc] + scr[1536+rr*256+cc] + b1c);
    }
    __syncthreads();                                   // [C]
    // --- layer 2: thread (g,i), register weights, 32-wide hidden slice
    {
      float c0 = 0.f, c1 = 0.f;
#pragma unroll
      for (int m = 0; m < 8; ++m) {
        c0 = fma4(w2r[m], hs4[g*8 + m], c0);          // broadcast reads
        c1 = fma4(w2r[m], hs4[64 + g*8 + m], c1);
      }
      scr[g*256 + i]       = c0;                      // p8[e][r][i]
      scr[g*256 + 128 + i] = c1;
    }
    __syncthreads();                                   // [D]
    if (tid < 256) {
      const float nv = scr[r2*128+i] + scr[256+r2*128+i] + scr[512+r2*128+i]
                     + scr[768+r2*128+i] + scr[1024+r2*128+i] + scr[1280+r2*128+i]
                     + scr[1536+r2*128+i] + scr[1792+r2*128+i] + b2i;
      if (ident) {
        u_reg = -nv;
        U[((size_t)t*BB + b0 + r2)*DD + i] = u_reg;
        wv[r2*128 + i] = sdt*nz + dt*u_reg;
        if (t < NS) lwloc += sdt*u_reg*nz - 0.5f*dt*u_reg*u_reg;
      } else {
        hs[r2*128 + i] = nv;                          // nv buffer (hs is dead)
      }
    }
    if (!ident) {
      __syncthreads();                                // nv ready, p8 reads done
      if (g < 4) {                                    // u = -nv @ sigma
        float s0 = 0.f, s1 = 0.f;
        const int kb = g*32;
#pragma unroll 8
        for (int kk = 0; kk < 32; ++kk) {
          const float sv = sigma[(kb+kk)*DD + i];
          s0 = fmaf(sv, hs[kb+kk], s0);
          s1 = fmaf(sv, hs[128+kb+kk], s1);
        }
        scr[g*256 + i]       = s0;
        scr[g*256 + 128 + i] = s1;
      }
      __syncthreads();
      if (tid < 256) {
        u_reg = -(scr[r2*128+i] + scr[256+r2*128+i] + scr[512+r2*128+i] + scr[768+r2*128+i]);
        U[((size_t)t*BB + b0 + r2)*DD + i] = u_reg;
        wv[r2*128 + i] = sdt*nz + dt*u_reg;
        if (t < NS) lwloc += sdt*u_reg*nz - 0.5f*dt*u_reg*u_reg;
      }
    }
    if (t == NS) break;
    __syncthreads();                                   // [E] wv ready; scr free
    // --- matvecs: g<4: A@x and A@wv (ident M2=-A) | M2row@wv (general)
    //              g>=4: P@x (+ wv@sigma^T general)
    if (g < 4) {
      float a0=0.f,a1=0.f,m0=0.f,m1=0.f;
      if (ident) {
#pragma unroll
        for (int m = 0; m < 8; ++m) {
          a0 = fma4(wr[m], xs4[g*8 + m], a0);
          a1 = fma4(wr[m], xs4[32 + g*8 + m], a1);
          m0 = fma4(wr[m], wv4[g*8 + m], m0);
          m1 = fma4(wr[m], wv4[32 + g*8 + m], m1);
        }
      } else {
#pragma unroll
        for (int m = 0; m < 8; ++m) {
          const float4 mv = *(const float4*)(M2row + i*DD + g*32 + 4*m);
          a0 = fma4(wr[m], xs4[g*8 + m], a0);
          a1 = fma4(wr[m], xs4[32 + g*8 + m], a1);
          m0 = fma4(mv, wv4[g*8 + m], m0);
          m1 = fma4(mv, wv4[32 + g*8 + m], m1);
        }
      }
      scr[g*256 + i]        = a0;   // pA
      scr[g*256 + 128 + i]  = a1;
      scr[1024 + g*256 + i] = m0;   // pM
      scr[1024 + g*256 + 128 + i] = m1;
    } else {
      const int gq = g - 4;
      float p0=0.f,p1=0.f;
#pragma unroll
      for (int m = 0; m < 8; ++m) {
        p0 = fma4(wr[m], xs4[gq*8 + m], p0);
        p1 = fma4(wr[m], xs4[32 + gq*8 + m], p1);
      }
      scr[2048 + gq*256 + i]       = p0;  // pP
      scr[2048 + gq*256 + 128 + i] = p1;
      if (!ident) {
        float s0=0.f,s1=0.f;
#pragma unroll
        for (int m = 0; m < 8; ++m) {
          const float4 sv = *(const float4*)(sigma + i*DD + gq*32 + 4*m);
          s0 = fma4(sv, wv4[gq*8 + m], s0);
          s1 = fma4(sv, wv4[32 + gq*8 + m], s1);
        }
        scr[3072 + gq*256 + i]       = s0;  // pS = wv@sigma^T
        scr[3072 + gq*256 + 128 + i] = s1;
      }
    }
    __syncthreads();                                   // [F]
    if (tid < 256) {
      const float xo = xs[r2*128 + i];
      const float xa = scr[r2*128+i] + scr[256+r2*128+i] + scr[512+r2*128+i] + scr[768+r2*128+i];
      float mm       = scr[1024+r2*128+i] + scr[1280+r2*128+i] + scr[1536+r2*128+i] + scr[1792+r2*128+i];
      const float yy = scr[2048+r2*128+i] + scr[2304+r2*128+i] + scr[2560+r2*128+i] + scr[2816+r2*128+i];
      float xn;
      if (ident) {
        mm = -mm;                                      // M2 = -A
        xn = xo + (xa + u_reg)*dt + sdt*nz;
      } else {
        const float sS = scr[3072+r2*128+i] + scr[3328+r2*128+i] + scr[3584+r2*128+i] + scr[3840+r2*128+i];
        xn = xo + xa*dt + sS;
      }
      TL[(size_t)(t+1)*(BB*DD) + (size_t)(b0 + r2)*DD + i] = dt*yy + mm;
      xs[r2*128 + i] = xn;
      lwloc += -0.5f*dt*xo*yy;
    }
  }
  // --- epilogue: TGT = x_NS @ Q^T, WGT = exp(lw - 0.5 x^T Q x)
  __syncthreads();
  {
    float q0 = 0.f, q1 = 0.f;
#pragma unroll
    for (int m = 0; m < 4; ++m) {
      const float4 qv = *(const float4*)(Qm + i*DD + g*16 + 4*m);
      q0 = fma4(qv, xs4[g*4 + m], q0);
      q1 = fma4(qv, xs4[32 + g*4 + m], q1);
    }
    scr[g*256 + i]       = q0;
    scr[g*256 + 128 + i] = q1;
  }
  __syncthreads();
  float qloc = 0.f;
  if (tid < 256) {
    float tt = 0.f;
#pragma unroll
    for (int e = 0; e < 8; ++e) tt += scr[e*256 + r2*128 + i];
    TGT[(b0 + r2)*DD + i] = tt;
    qloc = xs[r2*128 + i] * tt;
  }
  const float rq = wave_red(qloc);
  const float rl = wave_red(lwloc);
  if (tid < 256 && (tid & 63) == 0) { red[tid>>6] = rq; red[8 + (tid>>6)] = rl; }
  __syncthreads();
  if (tid == 0 || tid == 128) {
    const int r = tid >> 7;
    const float qf = red[2*r] + red[2*r + 1];
    const float lw = red[8 + 2*r] + red[8 + 2*r + 1];
    WGT[b0 + r] = expf(lw - 0.5f*qf);
  }
}

// ---- suffix scan over t (64k independent scans) + fused objective (ident)
__global__ __launch_bounds__(256) void k_scan(
    const float* __restrict__ TGT, const float* __restrict__ WGT,
    const float* __restrict__ U, float* __restrict__ TL,
    const int* __restrict__ FLG, float* __restrict__ PART_S)
{
  const int tid = threadIdx.x;
  const int bi = blockIdx.x*256 + tid;
  const int b = bi >> 7;
  const bool id = (*FLG != 0);
  const float w = WGT[b];
  float lst = TGT[bi];
  float obj = 0.f;
  if (id) { const float d = lst + U[(size_t)NS*(BB*DD) + bi]; obj = w*d*d; }
#pragma unroll 4
  for (int t = NS; t >= 1; --t) {
    const float v = TL[(size_t)t*(BB*DD) + bi];
    if (!id) TL[(size_t)t*(BB*DD) + bi] = lst;
    lst += v;
    if (id) { const float d = lst + U[(size_t)(t-1)*(BB*DD) + bi]; obj += w*d*d; }
  }
  if (!id) TL[bi] = lst;
  __shared__ float r4[4];
  const float s = wave_red(obj);
  if ((tid & 63) == 0) r4[tid >> 6] = s;
  __syncthreads();
  if (tid == 0) PART_S[blockIdx.x] = id ? (r4[0]+r4[1]+r4[2]+r4[3]) : 0.f;
}

// ---- general-sigma objective (no-op when sigma == I)
__global__ __launch_bounds__(256) void k_obj(
    const float* __restrict__ SG2row, const float* __restrict__ TL,
    const float* __restrict__ U, const float* __restrict__ WGT,
    const int* __restrict__ FLG, float* __restrict__ PART_O)
{
  const int blk = blockIdx.x;
  if (*FLG != 0) { if (threadIdx.x == 0) PART_O[blk] = 0.f; return; }
  const int t = blk >> 6, bg = blk & 63;
  __shared__ __align__(16) float ls[8][132];
  __shared__ __align__(16) float us[8][128];
  __shared__ __align__(16) float pD[2][8][128];
  __shared__ float wg[8];
  __shared__ float r4[4];
  const int tid = threadIdx.x;
  const int i = tid & 127, h = tid >> 7;
  for (int idx = tid; idx < 8*128; idx += 256) {
    const int rr = idx >> 7, k = idx & 127;
    ls[rr][k] = TL[(size_t)t*(BB*DD) + (size_t)(bg*8+rr)*DD + k];
    us[rr][k] = U [(size_t)t*(BB*DD) + (size_t)(bg*8+rr)*DD + k];
  }
  if (tid < 8) wg[tid] = WGT[bg*8 + tid];
  __syncthreads();
  const float* grow = SG2row + i*DD + h*64;
#pragma unroll
  for (int rr = 0; rr < 8; ++rr) {
    float a = 0.f;
#pragma unroll
    for (int it = 0; it < 16; ++it) {
      float4 gv = *(const float4*)(grow + it*4);
      float4 l4 = *(const float4*)&ls[rr][h*64 + it*4];
      a = fma4(gv, l4, a);
    }
    pD[h][rr][i] = a;
  }
  __syncthreads();
  float obj = 0.f;
#pragma unroll
  for (int p = 0; p < 4; ++p) {
    const int rr = h*4 + p;
    const float d = pD[0][rr][i] + pD[1][rr][i] + us[rr][i];
    obj += wg[rr]*d*d;
  }
  const float s = wave_red(obj);
  if ((tid & 63) == 0) r4[tid >> 6] = s;
  __syncthreads();
  if (tid == 0) PART_O[blk] = r4[0]+r4[1]+r4[2]+r4[3];
}

__global__ __launch_bounds__(256) void k_fin(
    const float* __restrict__ PART_S, const float* __restrict__ PART_O,
    float* __restrict__ out)
{
  const int tid = threadIdx.x;
  float s = PART_S[tid];
  for (int idx = tid; idx < NPO; idx += 256) s += PART_O[idx];
  __shared__ float r4[4];
  const float v = wave_red(s);
  if ((tid & 63) == 0) r4[tid >> 6] = v;
  __syncthreads();
  if (tid == 0) out[0] = (r4[0]+r4[1]+r4[2]+r4[3]) * (1.0f/((float)(NS+1)*(float)BB));
}

extern "C" void kernel_launch(void* const* d_in, const int* in_sizes, int n_in,
                              void* d_out, int out_size, void* d_ws, size_t ws_size,
                              hipStream_t stream) {
  (void)in_sizes; (void)n_in; (void)out_size; (void)ws_size;
  const float* x0     = (const float*)d_in[0];
  const float* sigma  = (const float*)d_in[1];
  const float* A      = (const float*)d_in[2];
  const float* P      = (const float*)d_in[3];
  const float* Q      = (const float*)d_in[4];
  const float* W1     = (const float*)d_in[5];
  const float* b1     = (const float*)d_in[6];
  const float* W2     = (const float*)d_in[7];
  const float* b2     = (const float*)d_in[8];
  const float* noises = (const float*)d_in[9];

  float* ws = (float*)d_ws;
  const size_t SL = (size_t)BB*DD;
  float* TL     = ws;
  float* U      = TL + (size_t)(NS+1)*SL;
  float* TGT    = U  + (size_t)(NS+1)*SL;
  float* WGT    = TGT + SL;
  float* M2row  = WGT + BB;
  float* SG2row = M2row + (size_t)DD*DD;
  float* SIT    = SG2row + (size_t)DD*DD;
  float* AUG    = SIT + (size_t)DD*DD;
  float* PART_S = AUG + (size_t)DD*256;
  float* PART_O = PART_S + 256;
  int*   FLG    = (int*)(PART_O + NPO);
  float* out    = (float*)d_out;

  (void)hipFuncSetAttribute((const void*)k_rollout,
                            hipFuncAttributeMaxDynamicSharedMemorySize, SMEM_BYTES);

  k_pre1<<<1, 256, 0, stream>>>(sigma, SIT, AUG, FLG);
  k_pre2<<<32, 256, 0, stream>>>(A, sigma, SIT, FLG, M2row, SG2row);
  k_rollout<<<NBLK, TPB, SMEM_BYTES, stream>>>(x0, sigma, W1, b1, W2, b2, noises,
                                               A, P, Q, M2row, FLG,
                                               U, TL, TGT, WGT);
  k_scan<<<(BB*DD)/256, 256, 0, stream>>>(TGT, WGT, U, TL, FLG, PART_S);
  k_obj<<<NPO, 256, 0, stream>>>(SG2row, TL, U, WGT, FLG, PART_O);
  k_fin<<<1, 256, 0, stream>>>(PART_S, PART_O, out);
}

// Round 8
// 3386.538 us; speedup vs baseline: 1.5012x; 1.5012x over previous
//
#include <hip/hip_runtime.h>
#include <math.h>

#define DD 128
#define HH 256
#define NS 300
#define BB 512
#define NBLK 256   // rollout blocks (2 rows each)
#define TPB 512
#define NPO (301*64)

// Dynamic-LDS float offsets for k_rollout
#define OFF_W1Q 0        // 32768 floats: [k4 0..31][hj 0..255] as float4
#define OFF_XS  32768    // [2][128]
#define OFF_HS  33024    // [2][256]  (general path reuses as xa/yy buffer in F1)
#define OFF_WV  33536    // [2][128]
#define OFF_NOI 33792    // [2][128] (general only)
#define OFF_NVU 34048    // [2][128] (general: nv, then u)
#define OFF_SCR 34304    // 6144 floats phase-shared partials
#define OFF_RED 40448    // 16
#define SMEM_FLOATS 40464
#define SMEM_BYTES (SMEM_FLOATS*4)   // 158.1 KB < 160 KB

__device__ __forceinline__ float tsf(int t){ return (float)((double)t*(1.0/(double)NS)); }

__device__ __forceinline__ float wave_red(float v){
#pragma unroll
  for(int o=32;o>0;o>>=1) v += __shfl_down(v,o);
  return v;
}
__device__ __forceinline__ float fma4(float4 a, float4 b, float acc){
  acc = fmaf(a.x,b.x,acc); acc = fmaf(a.y,b.y,acc);
  acc = fmaf(a.z,b.z,acc); acc = fmaf(a.w,b.w,acc); return acc;
}
__device__ __forceinline__ float4 fma_s4(float s, float4 w, float4 a){
  a.x = fmaf(s,w.x,a.x); a.y = fmaf(s,w.y,a.y);
  a.z = fmaf(s,w.z,a.z); a.w = fmaf(s,w.w,a.w); return a;
}

// ---- pre1: identity flag + (general) Gauss-Jordan inverse -> SIT = sigma^-T
__global__ __launch_bounds__(256) void k_pre1(
    const float* __restrict__ sigma,
    float* __restrict__ SIT, float* __restrict__ AUG, int* __restrict__ FLG)
{
  const int j = threadIdx.x;
  __shared__ int s_ok; __shared__ int s_p; __shared__ float s_fac[DD];
  if (j == 0) s_ok = 1;
  __syncthreads();
  bool ok = true;
  for (int idx = j; idx < DD*DD; idx += 256) {
    const int r = idx >> 7, c = idx & 127;
    if (sigma[idx] != (r==c ? 1.f : 0.f)) ok = false;
  }
  if (!ok) s_ok = 0;
  __syncthreads();
  const bool ident = (s_ok != 0);
  if (j == 0) *FLG = ident ? 1 : 0;
  if (ident) {
    for (int idx = j; idx < DD*DD; idx += 256) {
      const int r = idx >> 7, c = idx & 127;
      SIT[idx] = (r==c) ? 1.f : 0.f;
    }
    return;
  }
  for (int idx = j; idx < DD*256; idx += 256) {
    const int r = idx >> 8, c = idx & 255;
    AUG[idx] = (c < DD) ? sigma[r*DD + c] : ((c-DD)==r ? 1.f : 0.f);
  }
  __syncthreads();
  for (int c = 0; c < DD; ++c) {
    if (j == 0) {
      int p = c; float best = fabsf(AUG[c*256 + c]);
      for (int r2 = c+1; r2 < DD; ++r2) {
        const float v = fabsf(AUG[r2*256 + c]);
        if (v > best) { best = v; p = r2; }
      }
      s_p = p;
    }
    __syncthreads();
    const int p = s_p;
    if (p != c) {
      const float tmp = AUG[c*256 + j];
      AUG[c*256 + j] = AUG[p*256 + j];
      AUG[p*256 + j] = tmp;
    }
    __syncthreads();
    const float pd = AUG[c*256 + c];
    const float rowv = AUG[c*256 + j];
    __syncthreads();
    AUG[c*256 + j] = rowv / pd;
    if (j < DD) s_fac[j] = (j == c) ? 0.f : AUG[j*256 + c];
    __syncthreads();
    const float prj = AUG[c*256 + j];
    for (int r2 = 0; r2 < DD; ++r2) {
      if (r2 != c) AUG[r2*256 + j] -= s_fac[r2] * prj;
    }
    __syncthreads();
  }
  for (int idx = j; idx < DD*DD; idx += 256) {
    const int j2 = idx >> 7, k = idx & 127;
    SIT[idx] = AUG[k*256 + DD + j2];
  }
}

// ---- pre2: transposes AT/PT/QT/SGT ([k][i] = src[i][k]), M2T, SGC for k_obj
__global__ __launch_bounds__(256) void k_pre2(
    const float* __restrict__ A, const float* __restrict__ P,
    const float* __restrict__ Q, const float* __restrict__ sigma,
    const float* __restrict__ SIT, const int* __restrict__ FLG,
    float* __restrict__ ATm, float* __restrict__ PTm,
    float* __restrict__ QTm, float* __restrict__ SGTm,
    float* __restrict__ M2T, float* __restrict__ SGC)
{
  const int g = blockIdx.x*256 + threadIdx.x;
  const int gs = gridDim.x*256;
  const bool ident = (*FLG != 0);
  for (int idx = g; idx < DD*DD; idx += gs) {
    const int k = idx >> 7, i2 = idx & 127;   // dest [k][i2]
    ATm[idx]  = A[i2*DD + k];
    PTm[idx]  = P[i2*DD + k];
    QTm[idx]  = Q[i2*DD + k];
    SGTm[idx] = sigma[i2*DD + k];
    SGC[idx]  = sigma[i2*DD + k];  // SGC[k][i2]?? careful below
  }
  // SGC for k_obj must be SGC[i][k] = sigma[k][i]
  for (int idx = g; idx < DD*DD; idx += gs) {
    const int i2 = idx >> 7, k = idx & 127;
    SGC[idx] = sigma[k*DD + i2];
  }
  // M2T[k][i] = M2[i][k] = -(A @ sigma^-T)[i][k]
  for (int idx = g; idx < DD*DD; idx += gs) {
    const int k = idx >> 7, i2 = idx & 127;
    float m;
    if (ident) m = -A[i2*DD + k];
    else {
      float acc = 0.f;
      for (int j = 0; j < DD; ++j) acc = fmaf(A[i2*DD + j], SIT[j*DD + k], acc);
      m = -acc;
    }
    M2T[idx] = m;
  }
}

// ---- rollout: 256 blocks x 512 threads, 2 trajectories per block.
// W1 LDS-resident. W2/AT/PT streamed per step, coalesced (k-group, i4)
// mapping, with lifetime-disjoint register prefetch (W2 at phase A -> used C;
// AT/PT at phase D -> used E). No loop-invariant register arrays (128-VGPR
// budget, rounds 3-7 showed anything bigger spills).
__global__ __launch_bounds__(TPB) void k_rollout(
    const float* __restrict__ x0, const float* __restrict__ sigma,
    const float* __restrict__ W1, const float* __restrict__ b1,
    const float* __restrict__ W2, const float* __restrict__ b2,
    const float* __restrict__ noises,
    const float* __restrict__ AT, const float* __restrict__ PT,
    const float* __restrict__ QT, const float* __restrict__ SGT,
    const float* __restrict__ M2T, const int* __restrict__ FLG,
    float* __restrict__ U, float* __restrict__ TL,
    float* __restrict__ TGT, float* __restrict__ WGT)
{
  extern __shared__ float sm[];
  float4* W1q = (float4*)(sm + OFF_W1Q);
  float*  xs  = sm + OFF_XS;
  float*  hs  = sm + OFF_HS;
  float*  wv  = sm + OFF_WV;
  float*  noi = sm + OFF_NOI;
  float*  nvu = sm + OFF_NVU;
  float*  scr = sm + OFF_SCR;
  float*  red = sm + OFF_RED;
  float4* xs4 = (float4*)xs;     // row r at f4-offset r*32
  float4* hs4 = (float4*)hs;     // row r at f4-offset r*64
  float4* scr4 = (float4*)scr;

  const int tid = threadIdx.x;
  const int hj = tid & 255, hg = tid >> 8;       // layer-1 mapping
  const int i  = tid & 127;                      // tid<256 phases: r = tid>>7
  const int kq = tid >> 5, i4 = tid & 31;        // streaming matvec mapping
  const int b0 = blockIdx.x * 2;
  const bool ident = (*FLG != 0);

  // prologue: W1 rows 1..128 -> LDS as k-quads
  for (int idx = tid; idx < 8192; idx += TPB) {
    const int k4 = idx >> 8, h = idx & 255;
    float4 w;
    w.x = W1[(4*k4 + 1)*HH + h];
    w.y = W1[(4*k4 + 2)*HH + h];
    w.z = W1[(4*k4 + 3)*HH + h];
    w.w = W1[(4*k4 + 4)*HH + h];
    W1q[idx] = w;
  }
  const float w1t = W1[hj];          // time row
  const float b1c = b1[hj];
  const float b2i = b2[i];
  if (tid < 256) xs[tid] = x0[i];

  float lwloc = 0.f, u_reg = 0.f, nz = 0.f;

  for (int t = 0; t <= NS; ++t) {
    __syncthreads();                                   // [A] xs ready
    const float t0 = tsf(t);
    const float dt = tsf(t+1) - t0;
    const float sdt = sqrtf(dt);

    // --- early-issue W2 prefetch (used at phase C). Coalesced: lanes 0..31
    // read one contiguous 512B row chunk.
    float4 w2f[16];
#pragma unroll
    for (int kk = 0; kk < 16; ++kk)
      w2f[kk] = *(const float4*)&W2[(kq*16 + kk)*DD + i4*4];

    nz = 0.f;
    if (tid < 256 && t < NS) {
      nz = noises[((size_t)t*BB + b0 + (tid>>7))*DD + i];
      if (!ident) noi[tid] = nz;
    }

    // --- layer 1: thread (hj,hg) half-dot from LDS W1, both rows
    {
      float a0 = (hg == 0) ? t0*w1t : 0.f;
      float a1 = a0;
#pragma unroll
      for (int m = 0; m < 16; ++m) {
        const float4 w = W1q[(hg*16 + m)*256 + hj];
        a0 = fma4(w, xs4[hg*16 + m], a0);
        a1 = fma4(w, xs4[32 + hg*16 + m], a1);
      }
      scr[hg*512 + hj]       = a0;
      scr[hg*512 + 256 + hj] = a1;
    }
    __syncthreads();                                   // [B]
    {
      const int rr = tid >> 8, cc = tid & 255;
      hs[rr*256 + cc] = tanhf(scr[rr*256 + cc] + scr[512 + rr*256 + cc] + b1c);
    }
    __syncthreads();                                   // [C]
    // --- layer 2: thread (kq,i4), 16-k slice from w2f regs, hs broadcast
    {
      float4 c0 = make_float4(0,0,0,0), c1 = make_float4(0,0,0,0);
#pragma unroll
      for (int k4i = 0; k4i < 4; ++k4i) {
        const float4 h0 = hs4[kq*4 + k4i];
        const float4 h1 = hs4[64 + kq*4 + k4i];
        c0 = fma_s4(h0.x, w2f[k4i*4+0], c0); c1 = fma_s4(h1.x, w2f[k4i*4+0], c1);
        c0 = fma_s4(h0.y, w2f[k4i*4+1], c0); c1 = fma_s4(h1.y, w2f[k4i*4+1], c1);
        c0 = fma_s4(h0.z, w2f[k4i*4+2], c0); c1 = fma_s4(h1.z, w2f[k4i*4+2], c1);
        c0 = fma_s4(h0.w, w2f[k4i*4+3], c0); c1 = fma_s4(h1.w, w2f[k4i*4+3], c1);
      }
      scr4[kq*64 + i4]      = c0;     // [kq][r0][i4]
      scr4[kq*64 + 32 + i4] = c1;     // [kq][r1][i4]
    }
    __syncthreads();                                   // [D]
    // --- prefetch AT/PT for phase E (lifetime D->E; w2f dead)
    float4 mtf[16];
    if (t < NS) {
      const int kg = kq & 7;
      const float* Msrc = (kq < 8) ? AT : PT;
#pragma unroll
      for (int kk = 0; kk < 16; ++kk)
        mtf[kk] = *(const float4*)&Msrc[(kg*16 + kk)*DD + i4*4];
    }
    if (tid < 256) {
      const int r = tid >> 7;
      float nv = b2i;
#pragma unroll
      for (int g = 0; g < 16; ++g) nv += scr[g*256 + tid];
      if (ident) {
        u_reg = -nv;
        U[((size_t)t*BB + b0 + r)*DD + i] = u_reg;
        wv[tid] = sdt*nz + dt*u_reg;
        if (t < NS) lwloc += sdt*u_reg*nz - 0.5f*dt*u_reg*u_reg;
      } else {
        nvu[tid] = nv;
      }
    }
    if (!ident) {
      __syncthreads();                                 // [G1] nv ready
      {
        float4 s0 = make_float4(0,0,0,0), s1 = make_float4(0,0,0,0);
#pragma unroll
        for (int kk = 0; kk < 16; ++kk) {
          const float4 gv = *(const float4*)&sigma[(kq*16 + kk)*DD + i4*4];
          s0 = fma_s4(nvu[kq*16 + kk], gv, s0);
          s1 = fma_s4(nvu[128 + kq*16 + kk], gv, s1);
        }
        scr4[kq*64 + i4]      = s0;
        scr4[kq*64 + 32 + i4] = s1;
      }
      __syncthreads();                                 // [G2]
      if (tid < 256) {
        const int r = tid >> 7;
        float s = 0.f;
#pragma unroll
        for (int g = 0; g < 16; ++g) s += scr[g*256 + tid];
        u_reg = -s;
        U[((size_t)t*BB + b0 + r)*DD + i] = u_reg;
        nvu[tid] = u_reg;     // now holds u
        wv[tid] = sdt*nz + dt*u_reg;
        if (t < NS) lwloc += sdt*u_reg*nz - 0.5f*dt*u_reg*u_reg;
      }
    }
    if (t == NS) break;
    __syncthreads();                                   // [E] wv ready, scr free
    // --- streamed matvecs from mtf: kq<8: AT slice (x@AT, wv@AT);
    //     kq>=8: PT slice (P@x)
    {
      const int kg = kq & 7;
      if (kq < 8) {
        float4 ax0 = make_float4(0,0,0,0), ax1 = make_float4(0,0,0,0);
        float4 aw0 = make_float4(0,0,0,0), aw1 = make_float4(0,0,0,0);
#pragma unroll
        for (int kk = 0; kk < 16; ++kk) {
          const int k = kg*16 + kk;
          const float4 av = mtf[kk];
          ax0 = fma_s4(xs[k],       av, ax0);
          ax1 = fma_s4(xs[128 + k], av, ax1);
          aw0 = fma_s4(wv[k],       av, aw0);
          aw1 = fma_s4(wv[128 + k], av, aw1);
        }
        scr4[kg*128 + 0*32 + i4] = ax0;
        scr4[kg*128 + 1*32 + i4] = ax1;
        scr4[kg*128 + 2*32 + i4] = aw0;
        scr4[kg*128 + 3*32 + i4] = aw1;
      } else {
        float4 p0 = make_float4(0,0,0,0), p1 = make_float4(0,0,0,0);
#pragma unroll
        for (int kk = 0; kk < 16; ++kk) {
          const int k = kg*16 + kk;
          p0 = fma_s4(xs[k],       mtf[kk], p0);
          p1 = fma_s4(xs[128 + k], mtf[kk], p1);
        }
        scr4[1024 + kg*64 + i4]      = p0;
        scr4[1024 + kg*64 + 32 + i4] = p1;
      }
    }
    __syncthreads();                                   // [F]
    if (ident) {
      if (tid < 256) {
        const int r = tid >> 7;
        const float xo = xs[tid];
        float xa = 0.f, mm = 0.f, yy = 0.f;
#pragma unroll
        for (int g = 0; g < 8; ++g) {
          xa += scr[g*512 + r*128 + i];
          mm += scr[g*512 + 256 + r*128 + i];
          yy += scr[4096 + g*256 + r*128 + i];
        }
        mm = -mm;                                      // M2 = -A
        TL[(size_t)(t+1)*(BB*DD) + (size_t)(b0 + r)*DD + i] = dt*yy + mm;
        xs[tid] = xo + (xa + u_reg)*dt + sdt*nz;
        lwloc -= 0.5f*dt*xo*yy;
      }
    } else {
      // F1: reduce x@AT and P@x into hs (dead until next B)
      if (tid < 256) {
        const int r = tid >> 7;
        float xa = 0.f, yy = 0.f;
#pragma unroll
        for (int g = 0; g < 8; ++g) {
          xa += scr[g*512 + r*128 + i];
          yy += scr[4096 + g*256 + r*128 + i];
        }
        hs[tid] = xa; hs[256 + tid] = yy;
      }
      __syncthreads();                                 // [E2]
      {
        const int kg = kq & 7;
        if (kq < 8) {       // M2T @ wv
          float4 m0 = make_float4(0,0,0,0), m1 = make_float4(0,0,0,0);
#pragma unroll
          for (int kk = 0; kk < 16; ++kk) {
            const float4 mv = *(const float4*)&M2T[(kg*16 + kk)*DD + i4*4];
            m0 = fma_s4(wv[kg*16 + kk], mv, m0);
            m1 = fma_s4(wv[128 + kg*16 + kk], mv, m1);
          }
          scr4[kg*128 + 2*32 + i4] = m0;
          scr4[kg*128 + 3*32 + i4] = m1;
        } else {            // SGT @ u (u in nvu)
          float4 s0 = make_float4(0,0,0,0), s1 = make_float4(0,0,0,0);
#pragma unroll
          for (int kk = 0; kk < 16; ++kk) {
            const float4 sv = *(const float4*)&SGT[(kg*16 + kk)*DD + i4*4];
            s0 = fma_s4(nvu[kg*16 + kk], sv, s0);
            s1 = fma_s4(nvu[128 + kg*16 + kk], sv, s1);
          }
          scr4[1024 + kg*64 + i4]      = s0;
          scr4[1024 + kg*64 + 32 + i4] = s1;
        }
      }
      __syncthreads();                                 // [F2]
      if (tid < 256) {
        const int r = tid >> 7;
        float mm = 0.f, us = 0.f;
#pragma unroll
        for (int g = 0; g < 8; ++g) {
          mm += scr[g*512 + 256 + r*128 + i];
          us += scr[4096 + g*256 + r*128 + i];
        }
        wv[tid]  = mm;    // wv dead after E2
        nvu[tid] = us;    // u dead after E2
      }
      __syncthreads();                                 // [E3]
      if (kq >= 8) {       // SGT @ noise
        const int kg = kq & 7;
        float4 s0 = make_float4(0,0,0,0), s1 = make_float4(0,0,0,0);
#pragma unroll
        for (int kk = 0; kk < 16; ++kk) {
          const float4 sv = *(const float4*)&SGT[(kg*16 + kk)*DD + i4*4];
          s0 = fma_s4(noi[kg*16 + kk], sv, s0);
          s1 = fma_s4(noi[128 + kg*16 + kk], sv, s1);
        }
        scr4[1024 + kg*64 + i4]      = s0;
        scr4[1024 + kg*64 + 32 + i4] = s1;
      }
      __syncthreads();                                 // [F3]
      if (tid < 256) {
        const int r = tid >> 7;
        float ns = 0.f;
#pragma unroll
        for (int g = 0; g < 8; ++g) ns += scr[4096 + g*256 + r*128 + i];
        const float xo = xs[tid];
        const float xa = hs[tid], yy = hs[256 + tid];
        const float mm = wv[tid], us = nvu[tid];
        TL[(size_t)(t+1)*(BB*DD) + (size_t)(b0 + r)*DD + i] = dt*yy + mm;
        xs[tid] = xo + (xa + us)*dt + sdt*ns;
        lwloc -= 0.5f*dt*xo*yy;
      }
    }
  }
  // --- epilogue: TGT = x_NS @ Q^T, WGT = exp(lw - 0.5 x^T Q x)
  __syncthreads();
  {
    float4 q0 = make_float4(0,0,0,0), q1 = make_float4(0,0,0,0);
#pragma unroll
    for (int kk = 0; kk < 8; ++kk) {
      const int k = kq*8 + kk;
      const float4 qv = *(const float4*)&QT[k*DD + i4*4];
      q0 = fma_s4(xs[k],       qv, q0);
      q1 = fma_s4(xs[128 + k], qv, q1);
    }
    scr4[kq*64 + i4]      = q0;
    scr4[kq*64 + 32 + i4] = q1;
  }
  __syncthreads();
  float qloc = 0.f;
  if (tid < 256) {
    const int r = tid >> 7;
    float tt = 0.f;
#pragma unroll
    for (int g = 0; g < 16; ++g) tt += scr[g*256 + tid];
    TGT[(b0 + r)*DD + i] = tt;
    qloc = xs[tid]*tt;
  }
  const float rq = wave_red(qloc);
  const float rl = wave_red(lwloc);
  if ((tid & 63) == 0) { red[tid>>6] = rq; red[8 + (tid>>6)] = rl; }
  __syncthreads();
  if (tid == 0 || tid == 128) {
    const int r = tid >> 7;
    const float qf = red[2*r] + red[2*r + 1];
    const float lw = red[8 + 2*r] + red[8 + 2*r + 1];
    WGT[b0 + r] = expf(lw - 0.5f*qf);
  }
}

// ---- suffix scan over t (64k independent scans) + fused objective (ident)
__global__ __launch_bounds__(256) void k_scan(
    const float* __restrict__ TGT, const float* __restrict__ WGT,
    const float* __restrict__ U, float* __restrict__ TL,
    const int* __restrict__ FLG, float* __restrict__ PART_S)
{
  const int tid = threadIdx.x;
  const int bi = blockIdx.x*256 + tid;
  const int b = bi >> 7;
  const bool id = (*FLG != 0);
  const float w = WGT[b];
  float lst = TGT[bi];
  float obj = 0.f;
  if (id) { const float d = lst + U[(size_t)NS*(BB*DD) + bi]; obj = w*d*d; }
#pragma unroll 4
  for (int t = NS; t >= 1; --t) {
    const float v = TL[(size_t)t*(BB*DD) + bi];
    if (!id) TL[(size_t)t*(BB*DD) + bi] = lst;
    lst += v;
    if (id) { const float d = lst + U[(size_t)(t-1)*(BB*DD) + bi]; obj += w*d*d; }
  }
  if (!id) TL[bi] = lst;
  __shared__ float r4[4];
  const float s = wave_red(obj);
  if ((tid & 63) == 0) r4[tid >> 6] = s;
  __syncthreads();
  if (tid == 0) PART_S[blockIdx.x] = id ? (r4[0]+r4[1]+r4[2]+r4[3]) : 0.f;
}

// ---- general-sigma objective (no-op when sigma == I)
__global__ __launch_bounds__(256) void k_obj(
    const float* __restrict__ SGC, const float* __restrict__ TL,
    const float* __restrict__ U, const float* __restrict__ WGT,
    const int* __restrict__ FLG, float* __restrict__ PART_O)
{
  const int blk = blockIdx.x;
  if (*FLG != 0) { if (threadIdx.x == 0) PART_O[blk] = 0.f; return; }
  const int t = blk >> 6, bg = blk & 63;
  __shared__ __align__(16) float ls[8][132];
  __shared__ __align__(16) float us[8][128];
  __shared__ __align__(16) float pD[2][8][128];
  __shared__ float wg[8];
  __shared__ float r4[4];
  const int tid = threadIdx.x;
  const int i = tid & 127, h = tid >> 7;
  for (int idx = tid; idx < 8*128; idx += 256) {
    const int rr = idx >> 7, k = idx & 127;
    ls[rr][k] = TL[(size_t)t*(BB*DD) + (size_t)(bg*8+rr)*DD + k];
    us[rr][k] = U [(size_t)t*(BB*DD) + (size_t)(bg*8+rr)*DD + k];
  }
  if (tid < 8) wg[tid] = WGT[bg*8 + tid];
  __syncthreads();
  const float* grow = SGC + i*DD + h*64;
#pragma unroll
  for (int rr = 0; rr < 8; ++rr) {
    float a = 0.f;
#pragma unroll
    for (int it = 0; it < 16; ++it) {
      float4 gv = *(const float4*)(grow + it*4);
      float4 l4 = *(const float4*)&ls[rr][h*64 + it*4];
      a = fma4(gv, l4, a);
    }
    pD[h][rr][i] = a;
  }
  __syncthreads();
  float obj = 0.f;
#pragma unroll
  for (int p = 0; p < 4; ++p) {
    const int rr = h*4 + p;
    const float d = pD[0][rr][i] + pD[1][rr][i] + us[rr][i];
    obj += wg[rr]*d*d;
  }
  const float s = wave_red(obj);
  if ((tid & 63) == 0) r4[tid >> 6] = s;
  __syncthreads();
  if (tid == 0) PART_O[blk] = r4[0]+r4[1]+r4[2]+r4[3];
}

__global__ __launch_bounds__(256) void k_fin(
    const float* __restrict__ PART_S, const float* __restrict__ PART_O,
    float* __restrict__ out)
{
  const int tid = threadIdx.x;
  float s = PART_S[tid];
  for (int idx = tid; idx < NPO; idx += 256) s += PART_O[idx];
  __shared__ float r4[4];
  const float v = wave_red(s);
  if ((tid & 63) == 0) r4[tid >> 6] = v;
  __syncthreads();
  if (tid == 0) out[0] = (r4[0]+r4[1]+r4[2]+r4[3]) * (1.0f/((float)(NS+1)*(float)BB));
}

extern "C" void kernel_launch(void* const* d_in, const int* in_sizes, int n_in,
                              void* d_out, int out_size, void* d_ws, size_t ws_size,
                              hipStream_t stream) {
  (void)in_sizes; (void)n_in; (void)out_size; (void)ws_size;
  const float* x0     = (const float*)d_in[0];
  const float* sigma  = (const float*)d_in[1];
  const float* A      = (const float*)d_in[2];
  const float* P      = (const float*)d_in[3];
  const float* Q      = (const float*)d_in[4];
  const float* W1     = (const float*)d_in[5];
  const float* b1     = (const float*)d_in[6];
  const float* W2     = (const float*)d_in[7];
  const float* b2     = (const float*)d_in[8];
  const float* noises = (const float*)d_in[9];

  float* ws = (float*)d_ws;
  const size_t SL = (size_t)BB*DD;
  float* TL     = ws;
  float* U      = TL + (size_t)(NS+1)*SL;
  float* TGT    = U  + (size_t)(NS+1)*SL;
  float* WGT    = TGT + SL;
  float* ATm    = WGT + BB;
  float* PTm    = ATm + (size_t)DD*DD;
  float* QTm    = PTm + (size_t)DD*DD;
  float* SGTm   = QTm + (size_t)DD*DD;
  float* M2T    = SGTm + (size_t)DD*DD;
  float* SGC    = M2T + (size_t)DD*DD;
  float* SIT    = SGC + (size_t)DD*DD;
  float* AUG    = SIT + (size_t)DD*DD;
  float* PART_S = AUG + (size_t)DD*256;
  float* PART_O = PART_S + 256;
  int*   FLG    = (int*)(PART_O + NPO);
  float* out    = (float*)d_out;

  (void)hipFuncSetAttribute((const void*)k_rollout,
                            hipFuncAttributeMaxDynamicSharedMemorySize, SMEM_BYTES);

  k_pre1<<<1, 256, 0, stream>>>(sigma, SIT, AUG, FLG);
  k_pre2<<<32, 256, 0, stream>>>(A, P, Q, sigma, SIT, FLG,
                                 ATm, PTm, QTm, SGTm, M2T, SGC);
  k_rollout<<<NBLK, TPB, SMEM_BYTES, stream>>>(x0, sigma, W1, b1, W2, b2, noises,
                                               ATm, PTm, QTm, SGTm, M2T, FLG,
                                               U, TL, TGT, WGT);
  k_scan<<<(BB*DD)/256, 256, 0, stream>>>(TGT, WGT, U, TL, FLG, PART_S);
  k_obj<<<NPO, 256, 0, stream>>>(SGC, TL, U, WGT, FLG, PART_O);
  k_fin<<<1, 256, 0, stream>>>(PART_S, PART_O, out);
}